// Round 14
// baseline (280.754 us; speedup 1.0000x reference)
//
#include <hip/hip_runtime.h>
#include <hip/hip_bf16.h>
#include <hip/hip_cooperative_groups.h>
#include <math.h>

namespace cg = cooperative_groups;

#define NROWS 32768
#define DDIM  1024
#define NEXP  64
#define TAU   1e-4f
#define EPSF  1e-9f
#define CAPMAX 8192
#define NSHARD 8
#define NCH   16                 // chunks of BK=64 fp32 k (4 kc each)

typedef __attribute__((ext_vector_type(8)))  short  short8;
typedef __attribute__((ext_vector_type(16))) float  f32x16;
typedef __attribute__((address_space(3))) unsigned int       lds_u32;
typedef __attribute__((address_space(1))) const unsigned int g_u32;

// stable greater-than: value desc, index asc on ties (matches lax.top_k)
__device__ __forceinline__ bool gt_(float a, int ea, float b, int eb)
{ return a > b || (a == b && ea < eb); }

// split f into bf16 hi (RTNE) + bf16 lo (RTNE of exact residual).
__device__ __forceinline__ void cvt_hl(float f, short& h, short& l)
{
    __hip_bfloat16 hb = __float2bfloat16(f);
    float r = f - __bfloat162float(hb);
    __hip_bfloat16 lb = __float2bfloat16(r);
    h = *reinterpret_cast<short*>(&hb);
    l = *reinterpret_cast<short*>(&lb);
}

// ---------------------------------------------------------------------------
// ONE cooperative kernel, 3 phases separated by grid.sync():
//  P1: blocks 0..127 pack gate_w -> wp (per-lane MFMA B-fragment order,
//      bf16 hi+lo; lane-mapping HW-verified R5-R13); block 0 zeroes shard+cnt.
//  P2: R12/R13 main GEMM loop, byte-identical (proven 31.9 us):
//      grid 1024 x 128 thr, 32 rows/block, BK=64, x via 4-buffer
//      global_load_lds depth-3 pipeline (counted vmcnt), B via rotating regs.
//  P3: block 0 sums aux shards -> aux loss; blocks 1..1023 repair flagged
//      rows with exact fp32 logits (single pass for n < 1023).
// ---------------------------------------------------------------------------
__global__ __launch_bounds__(128, 2) void moe_fused(
    const float* __restrict__ x, const float* __restrict__ gw,
    unsigned short* __restrict__ wp, float* __restrict__ out,
    float* __restrict__ shard, int* __restrict__ cnt,
    int* __restrict__ list, int cap)
{
    extern __shared__ char smem[];          // 32 KB: x 4 x 8 KB

    const int t   = threadIdx.x;            // 0..127
    const int bid = blockIdx.x;             // 0..1023
    cg::grid_group grid = cg::this_grid();

    // ======================= PHASE 1: pack w =============================
    if (bid == 0) {
        if (t < 64) {
            #pragma unroll
            for (int s = 0; s < NSHARD; ++s) shard[s * 64 + t] = 0.0f;
        }
        if (t == 0) *cnt = 0;
    }
    if (bid < 128) {
        const int wid  = bid * 128 + t;     // 0..16383
        const int kc   = wid >> 8;          // 0..63
        const int ot   = wid & 255;         // old 256-thread index
        const int lane = ot & 63, gg = (ot >> 6) & 1, pr = ot >> 7;
        const int e = gg * 32 + (lane & 31);
        const int k = kc * 16 + (lane >> 5) * 8;
        float4 f0 = *reinterpret_cast<const float4*>(gw + (size_t)e * DDIM + k);
        float4 f1 = *reinterpret_cast<const float4*>(gw + (size_t)e * DDIM + k + 4);
        float f[8] = {f0.x, f0.y, f0.z, f0.w, f1.x, f1.y, f1.z, f1.w};
        short8 o;
        #pragma unroll
        for (int j = 0; j < 8; ++j) {
            short hh, ll;
            cvt_hl(f[j], hh, ll);
            o[j] = pr ? ll : hh;
        }
        *reinterpret_cast<short8*>(wp + ((size_t)((kc * 2 + gg) * 2 + pr) * 64 + lane) * 8) = o;
    }
    __threadfence();                        // device-scope visibility (XCD L2s)
    grid.sync();

    // ======================= PHASE 2: main GEMM ==========================
    {
        const int g = t >> 6;               // wave = expert half
        const int lane = t & 63;
        const int l31 = lane & 31, l5 = lane >> 5;
        const int row0 = bid * 32;
        const int arow = l31;
        const int xr   = (arow & 7) << 4;

        f32x16 acc;
        #pragma unroll
        for (int r = 0; r < 16; ++r) acc[r] = 0.0f;

        int srow[4], scol[4];
        #pragma unroll
        for (int q = 0; q < 4; ++q) {
            int d = q * 2048 + t * 16;
            srow[q] = d >> 8;
            scol[q] = (d & 255) ^ ((srow[q] & 7) << 4);
        }

        const char* wqb = (const char*)wp + (size_t)g * 2048 + (size_t)lane * 16;

        #define STAGE(c_) do {                                                   \
            const char* xs0_ = (const char*)x + (size_t)row0 * 4096 + (size_t)(c_) * 256; \
            const int xb_ = ((c_) & 3) * 8192;                                   \
            _Pragma("unroll")                                                    \
            for (int q_ = 0; q_ < 4; ++q_) {                                     \
                int d_ = q_ * 2048 + t * 16;                                     \
                const char* xsrc_ = xs0_ + (size_t)srow[q_] * 4096 + scol[q_];   \
                __builtin_amdgcn_global_load_lds((g_u32*)xsrc_,                  \
                    (lds_u32*)(smem + xb_ + d_), 16, 0, 0);                      \
            }                                                                    \
        } while (0)

        #define BLOAD(dst_, c_) do {                                             \
            _Pragma("unroll")                                                    \
            for (int kcl_ = 0; kcl_ < 4; ++kcl_) {                               \
                const char* b_ = wqb + (size_t)((c_) * 4 + kcl_) * 4096;         \
                dst_[kcl_][0] = *reinterpret_cast<const short8*>(b_);            \
                dst_[kcl_][1] = *reinterpret_cast<const short8*>(b_ + 1024);     \
            }                                                                    \
        } while (0)

        short8 Bc[4][2], Bn[4][2];

        STAGE(0); STAGE(1); STAGE(2);
        BLOAD(Bc, 0);

        for (int i = 0; i < NCH; ++i) {
            if (i < NCH - 1) BLOAD(Bn, i + 1);
            if (i < NCH - 3) STAGE(i + 3);
            __builtin_amdgcn_sched_barrier(0);
            if (i == 0)               { asm volatile("s_waitcnt vmcnt(12)" ::: "memory"); }
            else if (i < NCH - 3)     { asm volatile("s_waitcnt vmcnt(16)" ::: "memory"); }
            else if (i == NCH - 3)    { asm volatile("s_waitcnt vmcnt(12)" ::: "memory"); }
            else if (i == NCH - 2)    { asm volatile("s_waitcnt vmcnt(8)" ::: "memory"); }
            else                      { asm volatile("s_waitcnt vmcnt(0)" ::: "memory"); }
            __builtin_amdgcn_s_barrier();
            __builtin_amdgcn_sched_barrier(0);

            const int xb = (i & 3) * 8192;
            const char* xrow = smem + xb + arow * 256;
            #pragma unroll
            for (int kcl = 0; kcl < 4; ++kcl) {
                const int cb = kcl * 64 + l5 * 32;
                float4 f0 = *reinterpret_cast<const float4*>(xrow + (cb ^ xr));
                float4 f1 = *reinterpret_cast<const float4*>(xrow + ((cb + 16) ^ xr));
                float f[8] = {f0.x, f0.y, f0.z, f0.w, f1.x, f1.y, f1.z, f1.w};
                short8 ah, al;
                #pragma unroll
                for (int jj = 0; jj < 8; ++jj) {
                    short hh, ll;
                    cvt_hl(f[jj], hh, ll);
                    ah[jj] = hh; al[jj] = ll;
                }
                acc = __builtin_amdgcn_mfma_f32_32x32x16_bf16(ah, Bc[kcl][0], acc, 0, 0, 0);
                acc = __builtin_amdgcn_mfma_f32_32x32x16_bf16(al, Bc[kcl][0], acc, 0, 0, 0);
                acc = __builtin_amdgcn_mfma_f32_32x32x16_bf16(ah, Bc[kcl][1], acc, 0, 0, 0);
            }
            #pragma unroll
            for (int kcl = 0; kcl < 4; ++kcl) {
                Bc[kcl][0] = Bn[kcl][0];
                Bc[kcl][1] = Bn[kcl][1];
            }
            __builtin_amdgcn_sched_barrier(0);
            __builtin_amdgcn_s_barrier();
            __builtin_amdgcn_sched_barrier(0);
        }
        #undef STAGE
        #undef BLOAD

        // ---- logits -> LDS [32][68] f32 (C layout verified R5-R13) --------
        float* lgs = reinterpret_cast<float*>(smem);
        __syncthreads();
        #pragma unroll
        for (int r = 0; r < 16; ++r) {
            const int lrow = (r & 3) + 8 * (r >> 2) + 4 * l5;
            lgs[lrow * 68 + g * 32 + l31] = acc[r];
        }
        __syncthreads();

        // ---- row epilogue: 4 threads per row, 16 experts each -------------
        const int erow = t >> 2, q = t & 3;
        float L[16];
        #pragma unroll
        for (int i = 0; i < 4; ++i) {
            float4 v = *reinterpret_cast<const float4*>(lgs + erow * 68 + q * 16 + i * 4);
            L[4*i] = v.x; L[4*i+1] = v.y; L[4*i+2] = v.z; L[4*i+3] = v.w;
        }
        float v1 = -3.4e38f, v2 = -3.4e38f, v3 = -3.4e38f;
        int   e1 = 1 << 30,  e2 = 1 << 30,  e3 = 1 << 30;
        #pragma unroll
        for (int i = 0; i < 16; ++i) {
            float v = L[i]; int e = q * 16 + i;
            if      (gt_(v, e, v1, e1)) { v3=v2; e3=e2; v2=v1; e2=e1; v1=v; e1=e; }
            else if (gt_(v, e, v2, e2)) { v3=v2; e3=e2; v2=v; e2=e; }
            else if (gt_(v, e, v3, e3)) { v3=v; e3=e; }
        }
        #pragma unroll
        for (int m = 1; m <= 2; m <<= 1) {
            float o1 = __shfl_xor(v1, m), o2 = __shfl_xor(v2, m), o3 = __shfl_xor(v3, m);
            int  oe1 = __shfl_xor(e1, m), oe2 = __shfl_xor(e2, m), oe3 = __shfl_xor(e3, m);
            float n1, n2, n3; int m1, m2, m3;
            if (gt_(v1, e1, o1, oe1)) {
                n1 = v1; m1 = e1;
                if (gt_(v2, e2, o1, oe1)) {
                    n2 = v2; m2 = e2;
                    if (gt_(v3, e3, o1, oe1)) { n3 = v3; m3 = e3; } else { n3 = o1; m3 = oe1; }
                } else {
                    n2 = o1; m2 = oe1;
                    if (gt_(v2, e2, o2, oe2)) { n3 = v2; m3 = e2; } else { n3 = o2; m3 = oe2; }
                }
            } else {
                n1 = o1; m1 = oe1;
                if (gt_(o2, oe2, v1, e1)) {
                    n2 = o2; m2 = oe2;
                    if (gt_(o3, oe3, v1, e1)) { n3 = o3; m3 = oe3; } else { n3 = v1; m3 = e1; }
                } else {
                    n2 = v1; m2 = e1;
                    if (gt_(o2, oe2, v2, e2)) { n3 = o2; m3 = oe2; } else { n3 = v2; m3 = e2; }
                }
            }
            v1 = n1; e1 = m1; v2 = n2; e2 = m2; v3 = n3; e3 = m3;
        }
        float pr[16], sl = 0.0f;
        #pragma unroll
        for (int i = 0; i < 16; ++i) { pr[i] = expf(L[i] - v1); sl += pr[i]; }
        float S = sl;
        S += __shfl_xor(S, 1); S += __shfl_xor(S, 2);
        const float invS = 1.0f / S;
        #pragma unroll
        for (int i = 0; i < 16; ++i) pr[i] *= invS;
        #pragma unroll
        for (int m = 4; m <= 32; m <<= 1)
            #pragma unroll
            for (int i = 0; i < 16; ++i) pr[i] += __shfl_xor(pr[i], m);
        float* auxred = lgs + 32 * 68;      // 2 waves x 64 experts
        if (lane < 4) {
            #pragma unroll
            for (int i = 0; i < 16; ++i) auxred[g * 64 + q * 16 + i] = pr[i];
        }
        if (q == 0) {
            const float p1 = invS;
            const float p2 = expf(v2 - v1) * invS;
            const float dn = p1 + p2 + EPSF;
            const int r = row0 + erow;
            out[2 * r]                 = p1 / dn;
            out[2 * r + 1]             = p2 / dn;
            out[2 * NROWS + 2 * r]     = (float)e1;
            out[2 * NROWS + 2 * r + 1] = (float)e2;
            if (cap > 0 && (v1 - v2 < TAU || v2 - v3 < TAU)) {
                int pos = atomicAdd(cnt, 1);
                if (pos < cap) list[pos] = r;
            }
        }
        __syncthreads();
        if (t < 64) {
            float s = auxred[t] + auxred[64 + t];
            atomicAdd(&shard[(bid & (NSHARD - 1)) * 64 + t], s);
        }
    }
    __threadfence();
    grid.sync();

    // ======================= PHASE 3: aux + repairs ======================
    if (bid == 0) {
        if (t < 64) {
            float m = 0.0f;
            #pragma unroll
            for (int s = 0; s < NSHARD; ++s) m += shard[s * 64 + t];
            m *= (1.0f / (float)NROWS);
            float v = m * logf(m + EPSF);
            #pragma unroll
            for (int k = 1; k <= 32; k <<= 1) v += __shfl_xor(v, k);
            if (t == 0) out[4 * NROWS] = v;
        }
        return;
    }
    float* lg = reinterpret_cast<float*>(smem);   // 64 floats
    const int n = (cap > 0) ? min(*cnt, cap) : 0;
    const int e = t >> 1, part = t & 1;           // 64 experts x 2 K-halves
    for (int j = bid - 1; j < n; j += 1023) {
        const int row = list[j];
        const float* xrp = x  + (size_t)row * DDIM + part * 512;
        const float* wrp = gw + (size_t)e   * DDIM + part * 512;
        float a = 0.0f;
        #pragma unroll 8
        for (int kk = 0; kk < 128; ++kk) {
            float4 xv = *reinterpret_cast<const float4*>(xrp + kk * 4);
            float4 wv = *reinterpret_cast<const float4*>(wrp + kk * 4);
            a += xv.x * wv.x + xv.y * wv.y + xv.z * wv.z + xv.w * wv.w;
        }
        a += __shfl_xor(a, 1);                    // merge the two K-halves
        if (part == 0) lg[e] = a;
        __syncthreads();
        if (t < 4) {
            const int q = t;
            float v1 = -3.4e38f, v2 = -3.4e38f; int e1 = 1 << 30, e2 = 1 << 30;
            float Lr[16];
            #pragma unroll
            for (int i = 0; i < 16; ++i) {
                float v = Lr[i] = lg[q * 16 + i]; int ee = q * 16 + i;
                if      (gt_(v, ee, v1, e1)) { v2 = v1; e2 = e1; v1 = v; e1 = ee; }
                else if (gt_(v, ee, v2, e2)) { v2 = v; e2 = ee; }
            }
            #pragma unroll
            for (int m = 1; m <= 2; m <<= 1) {
                float o1 = __shfl_xor(v1, m), o2 = __shfl_xor(v2, m);
                int  oe1 = __shfl_xor(e1, m), oe2 = __shfl_xor(e2, m);
                float n1, n2; int m1, m2;
                if (gt_(v1, e1, o1, oe1)) {
                    n1 = v1; m1 = e1;
                    if (gt_(v2, e2, o1, oe1)) { n2 = v2; m2 = e2; } else { n2 = o1; m2 = oe1; }
                } else {
                    n1 = o1; m1 = oe1;
                    if (gt_(o2, oe2, v1, e1)) { n2 = o2; m2 = oe2; } else { n2 = v1; m2 = e1; }
                }
                v1 = n1; e1 = m1; v2 = n2; e2 = m2;
            }
            float s = 0.0f;
            #pragma unroll
            for (int i = 0; i < 16; ++i) s += expf(Lr[i] - v1);
            s += __shfl_xor(s, 1); s += __shfl_xor(s, 2);
            if (q == 0) {
                const float invS = 1.0f / s;
                const float p1 = invS, p2 = expf(v2 - v1) * invS;
                const float dn = p1 + p2 + EPSF;
                out[2 * row]                 = p1 / dn;
                out[2 * row + 1]             = p2 / dn;
                out[2 * NROWS + 2 * row]     = (float)e1;
                out[2 * NROWS + 2 * row + 1] = (float)e2;
            }
        }
        __syncthreads();
    }
}

extern "C" void kernel_launch(void* const* d_in, const int* in_sizes, int n_in,
                              void* d_out, int out_size, void* d_ws, size_t ws_size,
                              hipStream_t stream)
{
    const float* x  = (const float*)d_in[0];
    const float* gw = (const float*)d_in[1];
    float* out      = (float*)d_out;

    // d_ws layout: [wp 256KB][shard 2KB][cnt 4B pad->256B][list 32KB]
    unsigned short* wp = (unsigned short*)d_ws;
    float* shard   = (float*)((char*)d_ws + 262144);
    int*   cnt     = (int*)((char*)d_ws + 264192);
    int*   list    = (int*)((char*)d_ws + 264448);
    int cap = 0;
    if (ws_size >= 264448 + CAPMAX * sizeof(int)) cap = CAPMAX;
    else if (ws_size >= 264448 + 4096)
        cap = (int)((ws_size - 264448) / sizeof(int));

    void* args[] = { (void*)&x, (void*)&gw, (void*)&wp, (void*)&out,
                     (void*)&shard, (void*)&cnt, (void*)&list, (void*)&cap };
    hipLaunchCooperativeKernel(reinterpret_cast<void*>(&moe_fused),
                               dim3(1024), dim3(128), args, 32768, stream);
}

// Round 15
// 98.720 us; speedup vs baseline: 2.8439x; 2.8439x over previous
//
#include <hip/hip_runtime.h>
#include <hip/hip_bf16.h>
#include <math.h>

#define NROWS 32768
#define DDIM  1024
#define NEXP  64
#define TAU   1e-4f
#define EPSF  1e-9f
#define NSHARD 8
#define NCH   16                 // chunks of BK=64 fp32 k (4 kc each)
#define NBLK  1024

typedef __attribute__((ext_vector_type(8)))  short  short8;
typedef __attribute__((ext_vector_type(16))) float  f32x16;
typedef __attribute__((address_space(3))) unsigned int       lds_u32;
typedef __attribute__((address_space(1))) const unsigned int g_u32;

// stable greater-than: value desc, index asc on ties (matches lax.top_k)
__device__ __forceinline__ bool gt_(float a, int ea, float b, int eb)
{ return a > b || (a == b && ea < eb); }

// split f into bf16 hi (RTNE) + bf16 lo (RTNE of exact residual).
__device__ __forceinline__ void cvt_hl(float f, short& h, short& l)
{
    __hip_bfloat16 hb = __float2bfloat16(f);
    float r = f - __bfloat162float(hb);
    __hip_bfloat16 lb = __float2bfloat16(r);
    h = *reinterpret_cast<short*>(&hb);
    l = *reinterpret_cast<short*>(&lb);
}

// ---------------------------------------------------------------------------
// Pack gate_w ONCE into per-lane MFMA B-fragment order, bf16 hi+lo
// (fragment lane-mapping HW-verified R5-R14). Block 0 zeroes shards + done.
// ---------------------------------------------------------------------------
__global__ void wpack_kernel(const float* __restrict__ gw,
                             unsigned short* __restrict__ wp,
                             float* __restrict__ shard,
                             int* __restrict__ done)
{
    if (blockIdx.x == 0) {
        shard[threadIdx.x]       = 0.0f;
        shard[256 + threadIdx.x] = 0.0f;
        if (threadIdx.x == 0) *done = 0;
    }
    const int kc = blockIdx.x;              // 0..63
    const int t  = threadIdx.x;             // 256
    const int lane = t & 63, g = (t >> 6) & 1, pr = t >> 7;
    const int e = g * 32 + (lane & 31);
    const int k = kc * 16 + (lane >> 5) * 8;
    float4 f0 = *reinterpret_cast<const float4*>(gw + (size_t)e * DDIM + k);
    float4 f1 = *reinterpret_cast<const float4*>(gw + (size_t)e * DDIM + k + 4);
    float f[8] = {f0.x, f0.y, f0.z, f0.w, f1.x, f1.y, f1.z, f1.w};
    short8 o;
    #pragma unroll
    for (int j = 0; j < 8; ++j) {
        short hh, ll;
        cvt_hl(f[j], hh, ll);
        o[j] = pr ? ll : hh;
    }
    *reinterpret_cast<short8*>(wp + ((size_t)((kc * 2 + g) * 2 + pr) * 64 + lane) * 8) = o;
}

// ---------------------------------------------------------------------------
// Main (loop byte-identical R12, proven 31.9 us): grid 1024 x 128 thr,
// 32 rows/block, BK=64, x via 4-buffer global_load_lds depth-3 pipeline
// (counted vmcnt), B via rotating registers 1 chunk ahead.
// NEW: (a) ambiguous rows (margin < TAU) repaired IN-BLOCK with exact fp32;
//      (b) aux loss finished by the LAST block (device-scope done counter).
// No finalize kernel.
// ---------------------------------------------------------------------------
__global__ __launch_bounds__(128, 2) void moe_main(
    const float* __restrict__ x, const float* __restrict__ gw,
    const unsigned short* __restrict__ wp, float* __restrict__ out,
    float* __restrict__ shard, int* __restrict__ done)
{
    extern __shared__ char smem[];          // 32 KB: x 4 x 8 KB
    __shared__ unsigned ambig;

    const int t = threadIdx.x;              // 0..127
    const int g = t >> 6;                   // wave = expert half
    const int lane = t & 63;
    const int l31 = lane & 31, l5 = lane >> 5;
    const int row0 = blockIdx.x * 32;
    const int arow = l31;
    const int xr   = (arow & 7) << 4;

    if (t == 0) ambig = 0u;

    f32x16 acc;
    #pragma unroll
    for (int r = 0; r < 16; ++r) acc[r] = 0.0f;

    int srow[4], scol[4];
    #pragma unroll
    for (int q = 0; q < 4; ++q) {
        int d = q * 2048 + t * 16;
        srow[q] = d >> 8;
        scol[q] = (d & 255) ^ ((srow[q] & 7) << 4);
    }

    const char* wqb = (const char*)wp + (size_t)g * 2048 + (size_t)lane * 16;

    #define STAGE(c_) do {                                                       \
        const char* xs0_ = (const char*)x + (size_t)row0 * 4096 + (size_t)(c_) * 256; \
        const int xb_ = ((c_) & 3) * 8192;                                       \
        _Pragma("unroll")                                                        \
        for (int q_ = 0; q_ < 4; ++q_) {                                         \
            int d_ = q_ * 2048 + t * 16;                                         \
            const char* xsrc_ = xs0_ + (size_t)srow[q_] * 4096 + scol[q_];       \
            __builtin_amdgcn_global_load_lds((g_u32*)xsrc_,                      \
                (lds_u32*)(smem + xb_ + d_), 16, 0, 0);                          \
        }                                                                        \
    } while (0)

    #define BLOAD(dst_, c_) do {                                                 \
        _Pragma("unroll")                                                        \
        for (int kcl_ = 0; kcl_ < 4; ++kcl_) {                                   \
            const char* b_ = wqb + (size_t)((c_) * 4 + kcl_) * 4096;             \
            dst_[kcl_][0] = *reinterpret_cast<const short8*>(b_);                \
            dst_[kcl_][1] = *reinterpret_cast<const short8*>(b_ + 1024);         \
        }                                                                        \
    } while (0)

    short8 Bc[4][2], Bn[4][2];

    STAGE(0); STAGE(1); STAGE(2);
    BLOAD(Bc, 0);

    for (int i = 0; i < NCH; ++i) {
        if (i < NCH - 1) BLOAD(Bn, i + 1);
        if (i < NCH - 3) STAGE(i + 3);
        __builtin_amdgcn_sched_barrier(0);
        if (i == 0)               { asm volatile("s_waitcnt vmcnt(12)" ::: "memory"); }
        else if (i < NCH - 3)     { asm volatile("s_waitcnt vmcnt(16)" ::: "memory"); }
        else if (i == NCH - 3)    { asm volatile("s_waitcnt vmcnt(12)" ::: "memory"); }
        else if (i == NCH - 2)    { asm volatile("s_waitcnt vmcnt(8)" ::: "memory"); }
        else                      { asm volatile("s_waitcnt vmcnt(0)" ::: "memory"); }
        __builtin_amdgcn_s_barrier();
        __builtin_amdgcn_sched_barrier(0);

        const int xb = (i & 3) * 8192;
        const char* xrow = smem + xb + arow * 256;
        #pragma unroll
        for (int kcl = 0; kcl < 4; ++kcl) {
            const int cb = kcl * 64 + l5 * 32;
            float4 f0 = *reinterpret_cast<const float4*>(xrow + (cb ^ xr));
            float4 f1 = *reinterpret_cast<const float4*>(xrow + ((cb + 16) ^ xr));
            float f[8] = {f0.x, f0.y, f0.z, f0.w, f1.x, f1.y, f1.z, f1.w};
            short8 ah, al;
            #pragma unroll
            for (int jj = 0; jj < 8; ++jj) {
                short hh, ll;
                cvt_hl(f[jj], hh, ll);
                ah[jj] = hh; al[jj] = ll;
            }
            acc = __builtin_amdgcn_mfma_f32_32x32x16_bf16(ah, Bc[kcl][0], acc, 0, 0, 0);
            acc = __builtin_amdgcn_mfma_f32_32x32x16_bf16(al, Bc[kcl][0], acc, 0, 0, 0);
            acc = __builtin_amdgcn_mfma_f32_32x32x16_bf16(ah, Bc[kcl][1], acc, 0, 0, 0);
        }
        #pragma unroll
        for (int kcl = 0; kcl < 4; ++kcl) {
            Bc[kcl][0] = Bn[kcl][0];
            Bc[kcl][1] = Bn[kcl][1];
        }
        __builtin_amdgcn_sched_barrier(0);
        __builtin_amdgcn_s_barrier();
        __builtin_amdgcn_sched_barrier(0);
    }
    #undef STAGE
    #undef BLOAD

    // ---- logits -> LDS [32][68] f32 (C layout verified R5-R14) ------------
    float* lgs = reinterpret_cast<float*>(smem);
    __syncthreads();
    #pragma unroll
    for (int r = 0; r < 16; ++r) {
        const int lrow = (r & 3) + 8 * (r >> 2) + 4 * l5;
        lgs[lrow * 68 + g * 32 + l31] = acc[r];
    }
    __syncthreads();

    // ---- row epilogue: 4 threads per row, 16 experts each -----------------
    const int erow = t >> 2, q = t & 3;
    float L[16];
    #pragma unroll
    for (int i = 0; i < 4; ++i) {
        float4 v = *reinterpret_cast<const float4*>(lgs + erow * 68 + q * 16 + i * 4);
        L[4*i] = v.x; L[4*i+1] = v.y; L[4*i+2] = v.z; L[4*i+3] = v.w;
    }
    float v1 = -3.4e38f, v2 = -3.4e38f, v3 = -3.4e38f;
    int   e1 = 1 << 30,  e2 = 1 << 30,  e3 = 1 << 30;
    #pragma unroll
    for (int i = 0; i < 16; ++i) {
        float v = L[i]; int e = q * 16 + i;
        if      (gt_(v, e, v1, e1)) { v3=v2; e3=e2; v2=v1; e2=e1; v1=v; e1=e; }
        else if (gt_(v, e, v2, e2)) { v3=v2; e3=e2; v2=v; e2=e; }
        else if (gt_(v, e, v3, e3)) { v3=v; e3=e; }
    }
    #pragma unroll
    for (int m = 1; m <= 2; m <<= 1) {
        float o1 = __shfl_xor(v1, m), o2 = __shfl_xor(v2, m), o3 = __shfl_xor(v3, m);
        int  oe1 = __shfl_xor(e1, m), oe2 = __shfl_xor(e2, m), oe3 = __shfl_xor(e3, m);
        float n1, n2, n3; int m1, m2, m3;
        if (gt_(v1, e1, o1, oe1)) {
            n1 = v1; m1 = e1;
            if (gt_(v2, e2, o1, oe1)) {
                n2 = v2; m2 = e2;
                if (gt_(v3, e3, o1, oe1)) { n3 = v3; m3 = e3; } else { n3 = o1; m3 = oe1; }
            } else {
                n2 = o1; m2 = oe1;
                if (gt_(v2, e2, o2, oe2)) { n3 = v2; m3 = e2; } else { n3 = o2; m3 = oe2; }
            }
        } else {
            n1 = o1; m1 = oe1;
            if (gt_(o2, oe2, v1, e1)) {
                n2 = o2; m2 = oe2;
                if (gt_(o3, oe3, v1, e1)) { n3 = o3; m3 = oe3; } else { n3 = v1; m3 = e1; }
            } else {
                n2 = v1; m2 = e1;
                if (gt_(o2, oe2, v2, e2)) { n3 = o2; m3 = oe2; } else { n3 = v2; m3 = e2; }
            }
        }
        v1 = n1; e1 = m1; v2 = n2; e2 = m2; v3 = n3; e3 = m3;
    }
    float pr[16], sl = 0.0f;
    #pragma unroll
    for (int i = 0; i < 16; ++i) { pr[i] = expf(L[i] - v1); sl += pr[i]; }
    float S = sl;
    S += __shfl_xor(S, 1); S += __shfl_xor(S, 2);
    const float invS = 1.0f / S;
    #pragma unroll
    for (int i = 0; i < 16; ++i) pr[i] *= invS;
    #pragma unroll
    for (int m = 4; m <= 32; m <<= 1)
        #pragma unroll
        for (int i = 0; i < 16; ++i) pr[i] += __shfl_xor(pr[i], m);
    float* auxred = lgs + 32 * 68;          // 2 waves x 64 experts
    if (lane < 4) {
        #pragma unroll
        for (int i = 0; i < 16; ++i) auxred[g * 64 + q * 16 + i] = pr[i];
    }
    if (q == 0) {
        const float p1 = invS;
        const float p2 = expf(v2 - v1) * invS;
        const float dn = p1 + p2 + EPSF;
        const int r = row0 + erow;
        out[2 * r]                 = p1 / dn;
        out[2 * r + 1]             = p2 / dn;
        out[2 * NROWS + 2 * r]     = (float)e1;
        out[2 * NROWS + 2 * r + 1] = (float)e2;
        if (v1 - v2 < TAU || v2 - v3 < TAU)
            atomicOr(&ambig, 1u << erow);
    }
    __syncthreads();
    if (t < 64) {
        float s = auxred[t] + auxred[64 + t];
        atomicAdd(&shard[(blockIdx.x & (NSHARD - 1)) * 64 + t], s);
    }

    // ---- in-block fp32 repair of ambiguous rows (rare) --------------------
    unsigned am = ambig;
    if (am) {
        float* lg = lgs;                    // 64 floats scratch
        const int re = t >> 1, part = t & 1;
        while (am) {
            const int rloc = __ffs((int)am) - 1;
            am &= am - 1;
            const int row = row0 + rloc;
            const float* xrp = x  + (size_t)row * DDIM + part * 512;
            const float* wrp = gw + (size_t)re  * DDIM + part * 512;
            float a = 0.0f;
            #pragma unroll 8
            for (int kk = 0; kk < 128; ++kk) {
                float4 xv = *reinterpret_cast<const float4*>(xrp + kk * 4);
                float4 wv = *reinterpret_cast<const float4*>(wrp + kk * 4);
                a += xv.x * wv.x + xv.y * wv.y + xv.z * wv.z + xv.w * wv.w;
            }
            a += __shfl_xor(a, 1);          // merge the two K-halves
            __syncthreads();
            if (part == 0) lg[re] = a;
            __syncthreads();
            if (t < 4) {
                const int qq = t;
                float w1 = -3.4e38f, w2 = -3.4e38f; int f1i = 1 << 30, f2i = 1 << 30;
                float Lr[16];
                #pragma unroll
                for (int i = 0; i < 16; ++i) {
                    float v = Lr[i] = lg[qq * 16 + i]; int ee = qq * 16 + i;
                    if      (gt_(v, ee, w1, f1i)) { w2 = w1; f2i = f1i; w1 = v; f1i = ee; }
                    else if (gt_(v, ee, w2, f2i)) { w2 = v; f2i = ee; }
                }
                #pragma unroll
                for (int m = 1; m <= 2; m <<= 1) {
                    float o1 = __shfl_xor(w1, m), o2 = __shfl_xor(w2, m);
                    int  oe1 = __shfl_xor(f1i, m), oe2 = __shfl_xor(f2i, m);
                    float n1, n2; int m1, m2;
                    if (gt_(w1, f1i, o1, oe1)) {
                        n1 = w1; m1 = f1i;
                        if (gt_(w2, f2i, o1, oe1)) { n2 = w2; m2 = f2i; } else { n2 = o1; m2 = oe1; }
                    } else {
                        n1 = o1; m1 = oe1;
                        if (gt_(o2, oe2, w1, f1i)) { n2 = o2; m2 = oe2; } else { n2 = w1; m2 = f1i; }
                    }
                    w1 = n1; f1i = m1; w2 = n2; f2i = m2;
                }
                float s = 0.0f;
                #pragma unroll
                for (int i = 0; i < 16; ++i) s += expf(Lr[i] - w1);
                s += __shfl_xor(s, 1); s += __shfl_xor(s, 2);
                if (qq == 0) {
                    const float is = 1.0f / s;
                    const float p1 = is, p2 = expf(w2 - w1) * is;
                    const float dn = p1 + p2 + EPSF;
                    out[2 * row]                 = p1 / dn;
                    out[2 * row + 1]             = p2 / dn;
                    out[2 * NROWS + 2 * row]     = (float)f1i;
                    out[2 * NROWS + 2 * row + 1] = (float)f2i;
                }
            }
            __syncthreads();
        }
    }

    // ---- last block finishes the aux loss ---------------------------------
    __syncthreads();
    __threadfence();
    __shared__ int rank;
    if (t == 0) rank = atomicAdd(done, 1);
    __syncthreads();
    if (rank == NBLK - 1) {
        __threadfence();
        if (t < 64) {
            float m = 0.0f;
            #pragma unroll
            for (int s = 0; s < NSHARD; ++s) m += shard[s * 64 + t];
            m *= (1.0f / (float)NROWS);
            float v = m * logf(m + EPSF);
            #pragma unroll
            for (int k = 1; k <= 32; k <<= 1) v += __shfl_xor(v, k);
            if (t == 0) out[4 * NROWS] = v;
        }
    }
}

extern "C" void kernel_launch(void* const* d_in, const int* in_sizes, int n_in,
                              void* d_out, int out_size, void* d_ws, size_t ws_size,
                              hipStream_t stream)
{
    const float* x  = (const float*)d_in[0];
    const float* gw = (const float*)d_in[1];
    float* out      = (float*)d_out;

    // d_ws layout: [wp 256KB][shard 2KB][done 4B]
    unsigned short* wp = (unsigned short*)d_ws;
    float* shard = (float*)((char*)d_ws + 262144);
    int*   done  = (int*)((char*)d_ws + 264192);

    hipLaunchKernelGGL(wpack_kernel, dim3(64), dim3(256), 0, stream,
                       gw, wp, shard, done);
    hipLaunchKernelGGL(moe_main, dim3(NROWS / 32), dim3(128), 32768, stream,
                       x, gw, wp, out, shard, done);
}

// Round 16
// 62.276 us; speedup vs baseline: 4.5082x; 1.5852x over previous
//
#include <hip/hip_runtime.h>
#include <hip/hip_bf16.h>
#include <math.h>

#define NROWS 32768
#define DDIM  1024
#define NEXP  64
#define TAU   2e-4f
#define EPSF  1e-9f
#define CAPMAX 8192
#define NSHARD 8
#define NCH   32                 // chunks of BK=32 fp32 k (2 kc each)

typedef __attribute__((ext_vector_type(8)))  short  short8;
typedef __attribute__((ext_vector_type(16))) float  f32x16;
typedef __attribute__((address_space(3))) unsigned int       lds_u32;
typedef __attribute__((address_space(1))) const unsigned int g_u32;

// stable greater-than: value desc, index asc on ties (matches lax.top_k)
__device__ __forceinline__ bool gt_(float a, int ea, float b, int eb)
{ return a > b || (a == b && ea < eb); }

// split f into bf16 hi (RTNE) + bf16 lo (RTNE of exact residual).
__device__ __forceinline__ void cvt_hl(float f, short& h, short& l)
{
    __hip_bfloat16 hb = __float2bfloat16(f);
    float r = f - __bfloat162float(hb);
    __hip_bfloat16 lb = __float2bfloat16(r);
    h = *reinterpret_cast<short*>(&hb);
    l = *reinterpret_cast<short*>(&lb);
}

// ---------------------------------------------------------------------------
// Pack gate_w ONCE into per-lane MFMA B-fragment order, bf16 hi+lo
// (fragment lane-mapping HW-verified R5-R15). Block 0 zeroes shards + cnt.
// ---------------------------------------------------------------------------
__global__ void wpack_kernel(const float* __restrict__ gw,
                             unsigned short* __restrict__ wp,
                             float* __restrict__ shard,
                             int* __restrict__ cnt)
{
    if (blockIdx.x == 0) {
        shard[threadIdx.x]       = 0.0f;
        shard[256 + threadIdx.x] = 0.0f;
        if (threadIdx.x == 0) *cnt = 0;
    }
    const int kc = blockIdx.x;              // 0..63
    const int t  = threadIdx.x;             // 256
    const int lane = t & 63, g = (t >> 6) & 1, pr = t >> 7;
    const int e = g * 32 + (lane & 31);
    const int k = kc * 16 + (lane >> 5) * 8;
    float4 f0 = *reinterpret_cast<const float4*>(gw + (size_t)e * DDIM + k);
    float4 f1 = *reinterpret_cast<const float4*>(gw + (size_t)e * DDIM + k + 4);
    float f[8] = {f0.x, f0.y, f0.z, f0.w, f1.x, f1.y, f1.z, f1.w};
    short8 o;
    #pragma unroll
    for (int j = 0; j < 8; ++j) {
        short hh, ll;
        cvt_hl(f[j], hh, ll);
        o[j] = pr ? ll : hh;
    }
    *reinterpret_cast<short8*>(wp + ((size_t)((kc * 2 + g) * 2 + pr) * 64 + lane) * 8) = o;
}

// ---------------------------------------------------------------------------
// Main: BARRIER-FREE wave-self-paced pipeline. grid 1024 x 128 thr; block =
// 32 rows x 64 experts; wave g owns rows 0..31 x experts [g*32..), FULL K.
// Each wave has a PRIVATE 4-buffer x pipeline (BK=32, 4KB/buf, 16KB/wave):
// both waves stage the same x bytes (L2 MSHR-merged -> HBM once). NO
// s_barrier in the K-loop; each wave paces itself with counted vmcnt only
// (8 VMEM events/iter: BLOAD 4 + STAGE 4; steady vmcnt(24) ensures
// stage(i) landed with 3 iters in flight). One __syncthreads at epilogue.
// x swizzle both-sides (128-B rows): byte ^= ((row&7)<<4).
// ---------------------------------------------------------------------------
__global__ __launch_bounds__(128, 2) void moe_main(
    const float* __restrict__ x, const unsigned short* __restrict__ wp,
    float* __restrict__ out, float* __restrict__ shard,
    int* __restrict__ cnt, int* __restrict__ list, int cap)
{
    extern __shared__ char smem[];          // 32 KB: 2 waves x 4 bufs x 4 KB

    const int t = threadIdx.x;              // 0..127
    const int g = t >> 6;                   // wave = expert half
    const int lane = t & 63;
    const int l31 = lane & 31, l5 = lane >> 5;
    const int row0 = blockIdx.x * 32;
    const int arow = l31;                   // lane's x row within 32-row tile
    const int xr   = (arow & 7) << 4;       // read-side swizzle
    const int wbase = g * 16384;            // wave-private LDS region

    f32x16 acc;
    #pragma unroll
    for (int r = 0; r < 16; ++r) acc[r] = 0.0f;

    // staging map: 4 issues/chunk, d = q*1024 + lane*16 over [32 rows][128 B]
    int srow[4], scol[4];
    #pragma unroll
    for (int q = 0; q < 4; ++q) {
        srow[q] = q * 8 + (lane >> 3);
        scol[q] = ((lane & 7) << 4) ^ (((lane >> 3) & 7) << 4);
    }

    const char* wqb = (const char*)wp + (size_t)g * 2048 + (size_t)lane * 16;

    #define STAGE(c_) do {                                                       \
        const char* xs0_ = (const char*)x + (size_t)row0 * 4096 + (size_t)(c_) * 128; \
        const int xb_ = wbase + ((c_) & 3) * 4096;                               \
        _Pragma("unroll")                                                        \
        for (int q_ = 0; q_ < 4; ++q_) {                                         \
            const char* xsrc_ = xs0_ + (size_t)srow[q_] * 4096 + scol[q_];       \
            __builtin_amdgcn_global_load_lds((g_u32*)xsrc_,                      \
                (lds_u32*)(smem + xb_ + q_ * 1024 + lane * 16), 16, 0, 0);       \
        }                                                                        \
    } while (0)

    #define BLOAD(dst_, c_) do {                                                 \
        _Pragma("unroll")                                                        \
        for (int kcl_ = 0; kcl_ < 2; ++kcl_) {                                   \
            const char* b_ = wqb + (size_t)((c_) * 2 + kcl_) * 4096;             \
            dst_[kcl_][0] = *reinterpret_cast<const short8*>(b_);                \
            dst_[kcl_][1] = *reinterpret_cast<const short8*>(b_ + 1024);         \
        }                                                                        \
    } while (0)

    short8 Bc[2][2], Bn[2][2];

    // prologue: 3 chunks in flight, then B(0)
    STAGE(0); STAGE(1); STAGE(2);
    BLOAD(Bc, 0);

    for (int i = 0; i < NCH; ++i) {
        if (i < NCH - 1) BLOAD(Bn, i + 1);
        if (i < NCH - 3) STAGE(i + 3);
        __builtin_amdgcn_sched_barrier(0);
        if (i == 0)               { asm volatile("s_waitcnt vmcnt(20)" ::: "memory"); }
        else if (i < NCH - 3)     { asm volatile("s_waitcnt vmcnt(24)" ::: "memory"); }
        else if (i == NCH - 3)    { asm volatile("s_waitcnt vmcnt(20)" ::: "memory"); }
        else if (i == NCH - 2)    { asm volatile("s_waitcnt vmcnt(16)" ::: "memory"); }
        else                      { asm volatile("s_waitcnt vmcnt(8)"  ::: "memory"); }
        __builtin_amdgcn_sched_barrier(0);

        const char* xrow = smem + wbase + (i & 3) * 4096 + arow * 128;
        #pragma unroll
        for (int kcl = 0; kcl < 2; ++kcl) {
            const int cb = kcl * 64 + l5 * 32;          // within-row byte base
            float4 f0 = *reinterpret_cast<const float4*>(xrow + (cb ^ xr));
            float4 f1 = *reinterpret_cast<const float4*>(xrow + ((cb + 16) ^ xr));
            float f[8] = {f0.x, f0.y, f0.z, f0.w, f1.x, f1.y, f1.z, f1.w};
            short8 ah, al;
            #pragma unroll
            for (int jj = 0; jj < 8; ++jj) {
                short hh, ll;
                cvt_hl(f[jj], hh, ll);
                ah[jj] = hh; al[jj] = ll;
            }
            acc = __builtin_amdgcn_mfma_f32_32x32x16_bf16(ah, Bc[kcl][0], acc, 0, 0, 0);
            acc = __builtin_amdgcn_mfma_f32_32x32x16_bf16(al, Bc[kcl][0], acc, 0, 0, 0);
            acc = __builtin_amdgcn_mfma_f32_32x32x16_bf16(ah, Bc[kcl][1], acc, 0, 0, 0);
        }
        #pragma unroll
        for (int kcl = 0; kcl < 2; ++kcl) {
            Bc[kcl][0] = Bn[kcl][0];
            Bc[kcl][1] = Bn[kcl][1];
        }
        __builtin_amdgcn_sched_barrier(0);
    }
    #undef STAGE
    #undef BLOAD

    // ---- logits -> LDS [32][68] f32 (C layout verified R5-R15) ------------
    float* lgs = reinterpret_cast<float*>(smem);
    __syncthreads();                        // waves rejoin for the exchange
    #pragma unroll
    for (int r = 0; r < 16; ++r) {          // col=lane&31, row=(r&3)+8*(r>>2)+4*l5
        const int lrow = (r & 3) + 8 * (r >> 2) + 4 * l5;
        lgs[lrow * 68 + g * 32 + l31] = acc[r];
    }
    __syncthreads();

    // ---- row epilogue: 4 threads per row, 16 experts each (verified R5+) --
    const int erow = t >> 2, q = t & 3;
    float L[16];
    #pragma unroll
    for (int i = 0; i < 4; ++i) {
        float4 v = *reinterpret_cast<const float4*>(lgs + erow * 68 + q * 16 + i * 4);
        L[4*i] = v.x; L[4*i+1] = v.y; L[4*i+2] = v.z; L[4*i+3] = v.w;
    }
    float v1 = -3.4e38f, v2 = -3.4e38f, v3 = -3.4e38f;
    int   e1 = 1 << 30,  e2 = 1 << 30,  e3 = 1 << 30;
    #pragma unroll
    for (int i = 0; i < 16; ++i) {
        float v = L[i]; int e = q * 16 + i;
        if      (gt_(v, e, v1, e1)) { v3=v2; e3=e2; v2=v1; e2=e1; v1=v; e1=e; }
        else if (gt_(v, e, v2, e2)) { v3=v2; e3=e2; v2=v; e2=e; }
        else if (gt_(v, e, v3, e3)) { v3=v; e3=e; }
    }
    #pragma unroll
    for (int m = 1; m <= 2; m <<= 1) {      // merge the row's 4 lanes
        float o1 = __shfl_xor(v1, m), o2 = __shfl_xor(v2, m), o3 = __shfl_xor(v3, m);
        int  oe1 = __shfl_xor(e1, m), oe2 = __shfl_xor(e2, m), oe3 = __shfl_xor(e3, m);
        float n1, n2, n3; int m1, m2, m3;
        if (gt_(v1, e1, o1, oe1)) {
            n1 = v1; m1 = e1;
            if (gt_(v2, e2, o1, oe1)) {
                n2 = v2; m2 = e2;
                if (gt_(v3, e3, o1, oe1)) { n3 = v3; m3 = e3; } else { n3 = o1; m3 = oe1; }
            } else {
                n2 = o1; m2 = oe1;
                if (gt_(v2, e2, o2, oe2)) { n3 = v2; m3 = e2; } else { n3 = o2; m3 = oe2; }
            }
        } else {
            n1 = o1; m1 = oe1;
            if (gt_(o2, oe2, v1, e1)) {
                n2 = o2; m2 = oe2;
                if (gt_(o3, oe3, v1, e1)) { n3 = o3; m3 = oe3; } else { n3 = v1; m3 = e1; }
            } else {
                n2 = v1; m2 = e1;
                if (gt_(o2, oe2, v2, e2)) { n3 = o2; m3 = oe2; } else { n3 = v2; m3 = e2; }
            }
        }
        v1 = n1; e1 = m1; v2 = n2; e2 = m2; v3 = n3; e3 = m3;
    }
    float pr[16], sl = 0.0f;
    #pragma unroll
    for (int i = 0; i < 16; ++i) { pr[i] = expf(L[i] - v1); sl += pr[i]; }
    float S = sl;
    S += __shfl_xor(S, 1); S += __shfl_xor(S, 2);
    const float invS = 1.0f / S;
    #pragma unroll
    for (int i = 0; i < 16; ++i) pr[i] *= invS;
    #pragma unroll
    for (int m = 4; m <= 32; m <<= 1)
        #pragma unroll
        for (int i = 0; i < 16; ++i) pr[i] += __shfl_xor(pr[i], m);
    float* auxred = lgs + 32 * 68;          // 2 waves x 64 experts
    if (lane < 4) {
        #pragma unroll
        for (int i = 0; i < 16; ++i) auxred[g * 64 + q * 16 + i] = pr[i];
    }
    if (q == 0) {
        const float p1 = invS;
        const float p2 = expf(v2 - v1) * invS;
        const float dn = p1 + p2 + EPSF;
        const int r = row0 + erow;
        out[2 * r]                 = p1 / dn;
        out[2 * r + 1]             = p2 / dn;
        out[2 * NROWS + 2 * r]     = (float)e1;
        out[2 * NROWS + 2 * r + 1] = (float)e2;
        if (cap > 0 && (v1 - v2 < TAU || v2 - v3 < TAU)) {
            int pos = atomicAdd(cnt, 1);
            if (pos < cap) list[pos] = r;
        }
    }
    __syncthreads();
    if (t < 64) {
        float s = auxred[t] + auxred[64 + t];
        atomicAdd(&shard[(blockIdx.x & (NSHARD - 1)) * 64 + t], s);
    }
}

// ---------------------------------------------------------------------------
// Finalize (R12-verbatim): block 0 sums 8 aux shards -> aux loss; blocks
// 1..64 repair flagged rows with exact fp32 logits.
// ---------------------------------------------------------------------------
__global__ __launch_bounds__(256) void finalize_kernel(
    const float* __restrict__ x, const float* __restrict__ gw,
    float* __restrict__ out, const float* __restrict__ shard,
    const int* __restrict__ cnt, const int* __restrict__ list, int cap)
{
    if (blockIdx.x == 0) {
        const int tt = threadIdx.x;
        if (tt < 64) {
            float m = 0.0f;
            #pragma unroll
            for (int s = 0; s < NSHARD; ++s) m += shard[s * 64 + tt];
            m *= (1.0f / (float)NROWS);
            float v = m * logf(m + EPSF);
            #pragma unroll
            for (int k = 1; k <= 32; k <<= 1) v += __shfl_xor(v, k);
            if (tt == 0) out[4 * NROWS] = v;
        }
        return;
    }
    __shared__ float lg[64];
    const int n = (cap > 0) ? min(*cnt, cap) : 0;
    const int tt = threadIdx.x, e = tt >> 2, part = tt & 3;
    for (int j = (int)blockIdx.x - 1; j < n; j += 64) {
        const int row = list[j];
        const float* xrp = x  + (size_t)row * DDIM + part * 256;
        const float* wrp = gw + (size_t)e   * DDIM + part * 256;
        float a = 0.0f;
        #pragma unroll 8
        for (int kk = 0; kk < 64; ++kk) {
            float4 xv = *reinterpret_cast<const float4*>(xrp + kk * 4);
            float4 wv = *reinterpret_cast<const float4*>(wrp + kk * 4);
            a += xv.x * wv.x + xv.y * wv.y + xv.z * wv.z + xv.w * wv.w;
        }
        a += __shfl_xor(a, 1); a += __shfl_xor(a, 2);
        if (part == 0) lg[e] = a;
        __syncthreads();
        if (tt < 4) {
            const int q = tt;
            float v1 = -3.4e38f, v2 = -3.4e38f; int e1 = 1 << 30, e2 = 1 << 30;
            float Lr[16];
            #pragma unroll
            for (int i = 0; i < 16; ++i) {
                float v = Lr[i] = lg[q * 16 + i]; int ee = q * 16 + i;
                if      (gt_(v, ee, v1, e1)) { v2 = v1; e2 = e1; v1 = v; e1 = ee; }
                else if (gt_(v, ee, v2, e2)) { v2 = v; e2 = ee; }
            }
            #pragma unroll
            for (int m = 1; m <= 2; m <<= 1) {
                float o1 = __shfl_xor(v1, m), o2 = __shfl_xor(v2, m);
                int  oe1 = __shfl_xor(e1, m), oe2 = __shfl_xor(e2, m);
                float n1, n2; int m1, m2;
                if (gt_(v1, e1, o1, oe1)) {
                    n1 = v1; m1 = e1;
                    if (gt_(v2, e2, o1, oe1)) { n2 = v2; m2 = e2; } else { n2 = o1; m2 = oe1; }
                } else {
                    n1 = o1; m1 = oe1;
                    if (gt_(o2, oe2, v1, e1)) { n2 = o2; m2 = oe2; } else { n2 = v1; m2 = e1; }
                }
                v1 = n1; e1 = m1; v2 = n2; e2 = m2;
            }
            float s = 0.0f;
            #pragma unroll
            for (int i = 0; i < 16; ++i) s += expf(Lr[i] - v1);
            s += __shfl_xor(s, 1); s += __shfl_xor(s, 2);
            if (q == 0) {
                const float invS = 1.0f / s;
                const float p1 = invS, p2 = expf(v2 - v1) * invS;
                const float dn = p1 + p2 + EPSF;
                out[2 * row]                 = p1 / dn;
                out[2 * row + 1]             = p2 / dn;
                out[2 * NROWS + 2 * row]     = (float)e1;
                out[2 * NROWS + 2 * row + 1] = (float)e2;
            }
        }
        __syncthreads();
    }
}

extern "C" void kernel_launch(void* const* d_in, const int* in_sizes, int n_in,
                              void* d_out, int out_size, void* d_ws, size_t ws_size,
                              hipStream_t stream)
{
    const float* x  = (const float*)d_in[0];
    const float* gw = (const float*)d_in[1];
    float* out      = (float*)d_out;

    // d_ws layout: [wp 256KB][shard 2KB][cnt 4B pad->256B][list ...]
    unsigned short* wp = (unsigned short*)d_ws;
    float* shard   = (float*)((char*)d_ws + 262144);
    int*   cnt     = (int*)((char*)d_ws + 264192);
    int*   list    = (int*)((char*)d_ws + 264448);
    int cap = 0;
    if (ws_size >= 264448 + 4096) {
        size_t avail = (ws_size - 264448) / sizeof(int);
        cap = (avail > CAPMAX) ? CAPMAX : (int)avail;
    }

    hipLaunchKernelGGL(wpack_kernel, dim3(64), dim3(256), 0, stream,
                       gw, wp, shard, cnt);
    hipLaunchKernelGGL(moe_main, dim3(NROWS / 32), dim3(128), 32768, stream,
                       x, wp, out, shard, cnt, list, cap);
    hipLaunchKernelGGL(finalize_kernel, dim3(65), dim3(256), 0, stream,
                       x, gw, out, shard, cnt, list, cap);
}